// Round 19
// baseline (234.094 us; speedup 1.0000x reference)
//
#include <hip/hip_runtime.h>

#define N_NODES 6000
#define DEG_    16
#define N_EDGES (N_NODES*DEG_)
#define D_MODEL 256
#define D_MSG   64
#define D_FF    1024

#define TBL_N   1024
#define TBL_DMAX 9.0f

typedef __bf16 bf16x8 __attribute__((ext_vector_type(8)));
typedef float floatx4 __attribute__((ext_vector_type(4)));

__device__ __forceinline__ float silu_f(float v) {
    return v * __builtin_amdgcn_rcpf(1.0f + __expf(-v));
}
__device__ __forceinline__ float b2f(unsigned short u) {
    union { unsigned int i; float f; } v; v.i = ((unsigned int)u) << 16; return v.f;
}
__device__ __forceinline__ unsigned short f2b(float f) {
    union { float f; unsigned int i; } v; v.f = f;
    unsigned int r = (v.i + 0x7FFFu + ((v.i >> 16) & 1u)) >> 16;
    return (unsigned short)r;
}

// ---------------- prep: geom + W1 pack + wsrc/wdst pack + Wedge pack (no embed relay) ----------
#define GEOM_BLOCKS (N_EDGES/256)              // 375
#define WPACK1_BLOCKS 96                       // W1 pack (3 layers): 24576 lane-frags
#define WSDP_BLOCKS 16                         // wsrc/wdst pack: 4096 lane-frags
#define WPACKE_BLOCKS 24                       // Wedge pack: 6144 lane-frags
__global__ __launch_bounds__(256) void prep_kernel(
    const float* __restrict__ Wsrc, const float* __restrict__ Wdst,
    const float* __restrict__ W1, const float* __restrict__ Wedge,
    const float* __restrict__ r, float* __restrict__ d, float* __restrict__ rhat,
    unsigned short* __restrict__ w1p,        // PACKED [3 layers][8192 frags][8]
    unsigned short* __restrict__ wsdp,       // PACKED [8 tiles][8 ks][64 lane][8]
    unsigned short* __restrict__ wedgep) {   // PACKED [6144 frags][8]
    int b = blockIdx.x;
    int t = threadIdx.x;
    if (b < GEOM_BLOCKS) {
        int e = b*256 + t;
        float xx = r[e*3+0], yy = r[e*3+1], zz = r[e*3+2];
        float n = sqrtf(xx*xx + yy*yy + zz*zz);
        d[e] = n;
        float inv = 1.0f / n;
        *(float4*)(rhat + (size_t)e*4) = make_float4(xx*inv, yy*inv, zz*inv, 0.f);
    } else if (b < GEOM_BLOCKS + WPACK1_BLOCKS) {
        // W1 fragment pack (3 layers): i2 = lp*8192 + f*512 + wv*128 + j*64 + lane
        int wb = b - GEOM_BLOCKS;
        int i2 = wb*256 + t;                 // 0..24575
        int lp = i2 >> 13;                   // 0..2
        int e = i2 & 8191;
        int lane = e & 63, j = (e >> 6) & 1, wv = (e >> 7) & 3, f = e >> 9;
        int row = f*64 + wv*16 + (lane & 15);
        int col = j*32 + (lane >> 4)*8;
        const float* sp = W1 + (size_t)lp*65536 + (size_t)row*64 + col;
        float4 v0 = *(const float4*)sp;
        float4 v1 = *(const float4*)(sp + 4);
        unsigned short h[8] = { f2b(v0.x), f2b(v0.y), f2b(v0.z), f2b(v0.w),
                                f2b(v1.x), f2b(v1.y), f2b(v1.z), f2b(v1.w) };
        *(uint4*)(w1p + (size_t)i2*8) = *(uint4*)h;
    } else if (b < GEOM_BLOCKS + WPACK1_BLOCKS + WSDP_BLOCKS) {
        // wsrc/wdst fragment pack (layer 0): i = tl*512 + ks*64 + lane, tl = bx*4+ns
        int wb = b - (GEOM_BLOCKS + WPACK1_BLOCKS);
        int i = wb*256 + t;                  // 0..4095
        int lane = i & 63, ks = (i >> 6) & 7, tl = i >> 9;   // tl 0..7
        int bx = tl >> 2, ns = tl & 3;
        int row = ns*16 + (lane & 15);
        int col = ks*32 + (lane >> 4)*8;
        const float* sp = (bx ? Wdst : Wsrc) + (size_t)row*256 + col;
        float4 v0 = *(const float4*)sp;
        float4 v1 = *(const float4*)(sp + 4);
        unsigned short h[8] = { f2b(v0.x), f2b(v0.y), f2b(v0.z), f2b(v0.w),
                                f2b(v1.x), f2b(v1.y), f2b(v1.z), f2b(v1.w) };
        *(uint4*)(wsdp + (size_t)i*8) = *(uint4*)h;
    } else {
        // Wedge fragment pack: i = ((w*3+ns)*8+ks)*64 + lane, i in [0,6144)
        int wb = b - (GEOM_BLOCKS + WPACK1_BLOCKS + WSDP_BLOCKS);
        int i = wb*256 + t;                  // 0..6143
        int lane = i & 63, ks = (i >> 6) & 7, rem = i >> 9;   // rem 0..11
        int ns = rem % 3, w = rem / 3;                        // w 0..3
        int row = 48*w + ns*16 + (lane & 15);
        int col = ks*32 + (lane >> 4)*8;
        const float* sp = Wedge + (size_t)row*256 + col;
        float4 v0 = *(const float4*)sp;
        float4 v1 = *(const float4*)(sp + 4);
        unsigned short h[8] = { f2b(v0.x), f2b(v0.y), f2b(v0.z), f2b(v0.w),
                                f2b(v1.x), f2b(v1.y), f2b(v1.z), f2b(v1.w) };
        *(uint4*)(wedgep + (size_t)i*8) = *(uint4*)h;
    }
}

// ---------------- merged: gemm0 [0,375) + wcomb/wfc2/bcomb [375,444) + MFMA table [444,460) ----
__global__ __launch_bounds__(256) void eplg_kernel(
    const int* __restrict__ an, const float* __restrict__ emb,
    const unsigned short* __restrict__ wsdp, // PACKED wsrc/wdst frags
    const float* __restrict__ bias1,         // bsrc
    const float* __restrict__ bias2,         // bdst
    unsigned short* __restrict__ Cg,         // d_xjxi [N,128]
    const float* __restrict__ Wsrc, const float* __restrict__ Wdst,
    const float* __restrict__ W2, const float* __restrict__ b2,
    const float* __restrict__ Wfc, const float* __restrict__ bfc,
    unsigned short* __restrict__ wcomb,      // PACKED [2 layers][16384 frags][8]
    float* __restrict__ bcomb,
    float* __restrict__ wfc2,
    const unsigned short* __restrict__ Bwp,  // PACKED Wedge frags
    const float* __restrict__ bedge,         // [192]
    unsigned short* __restrict__ T,          // [TBL_N,192] bf16 out
    float* __restrict__ out) {
    const int t = threadIdx.x;
    const int w = t >> 6, lane = t & 63, lr = lane & 15, lq = lane >> 4;

    if (blockIdx.x < 375) {
        // ================= layer0 GEMM, barrier-free, fused embed gather =================
        const int m0 = blockIdx.x * 16;
        const float* erow = emb + (size_t)an[m0 + lr]*D_MODEL;
        bf16x8 af[8];
        #pragma unroll
        for (int ks = 0; ks < 8; ++ks) {
            float4 v0 = *(const float4*)(erow + ks*32 + lq*8);
            float4 v1 = *(const float4*)(erow + ks*32 + lq*8 + 4);
            unsigned short h[8] = { f2b(v0.x), f2b(v0.y), f2b(v0.z), f2b(v0.w),
                                    f2b(v1.x), f2b(v1.y), f2b(v1.z), f2b(v1.w) };
            af[ks] = *(bf16x8*)h;
        }
        #pragma unroll
        for (int h = 0; h < 2; ++h) {
            int tl = w*2 + h;                // 0..7
            int bx = tl >> 2, ns = tl & 3;
            const unsigned short* pbase = wsdp + ((size_t)tl*512 + lane)*8;
            uint4 pb[8];
            #pragma unroll
            for (int ks = 0; ks < 8; ++ks)
                pb[ks] = *(const uint4*)(pbase + ks*512);
            floatx4 acc = {};
            #pragma unroll
            for (int ks = 0; ks < 8; ++ks)
                acc = __builtin_amdgcn_mfma_f32_16x16x32_bf16(
                    af[ks], *(const bf16x8*)&pb[ks], acc, 0, 0, 0);
            int col = bx*64 + ns*16 + lr;
            float bv = (bx ? bias2 : bias1)[ns*16 + lr];
            #pragma unroll
            for (int rg = 0; rg < 4; ++rg) {
                int gm = m0 + lq*4 + rg;
                Cg[(size_t)gm*128 + col] = f2b(acc[rg] + bv);
            }
        }
        return;
    }
    if (blockIdx.x < 444) {
        // ================= wcomb/wfc2/bcomb branch =================
        int b = blockIdx.x - 375;        // 0..68
        if (b < 64) {
            int lp  = 1 + (b >> 5);      // layer index 1,2
            int wb2 = b & 31;            // 32 blocks/layer
            const float* W2f = W2 + (size_t)(lp-1)*262144;
            const float* wm[4];
            #pragma unroll
            for (int i = 0; i < 4; ++i) {
                int row = wb2*4 + i;
                wm[i] = (row < 64) ? (Wsrc + (size_t)lp*16384 + row*256)
                                   : (Wdst + (size_t)lp*16384 + (row-64)*256);
            }
            float acc[4][4] = {};
            int c0 = t*4;
            #pragma unroll 8
            for (int c = 0; c < 256; ++c) {
                float4 w2v = *(const float4*)(W2f + (size_t)c*1024 + c0);
                #pragma unroll
                for (int i = 0; i < 4; ++i) {
                    float wv2 = wm[i][c];
                    acc[i][0] = fmaf(wv2, w2v.x, acc[i][0]);
                    acc[i][1] = fmaf(wv2, w2v.y, acc[i][1]);
                    acc[i][2] = fmaf(wv2, w2v.z, acc[i][2]);
                    acc[i][3] = fmaf(wv2, w2v.w, acc[i][3]);
                }
            }
            int fc = t >> 4, j = (t >> 3) & 1, lq2 = (t >> 1) & 3, cpos = (t & 1) * 4;
            #pragma unroll
            for (int i = 0; i < 4; ++i) {
                int row = wb2*4 + i;
                int wv2 = row >> 5, ns = (row >> 4) & 1, lr2 = row & 15;
                *(ushort4*)(wcomb + (size_t)(lp-1)*131072
                            + (size_t)fc*8192 + wv2*2048 + ns*1024 + j*512 + (lq2*16+lr2)*8 + cpos) =
                    make_ushort4(f2b(acc[i][0]), f2b(acc[i][1]), f2b(acc[i][2]), f2b(acc[i][3]));
            }
        } else if (b < 68) {
            int c = (b - 64)*256 + t;
            const float* W2f = W2 + 2*262144;
            float a[8] = {};
            #pragma unroll 4
            for (int k = 0; k < 256; k += 8) {
                #pragma unroll
                for (int j = 0; j < 8; ++j)
                    a[j] = fmaf(Wfc[k+j], W2f[(size_t)(k+j)*1024 + c], a[j]);
            }
            wfc2[c] = ((a[0]+a[1]) + (a[2]+a[3])) + ((a[4]+a[5]) + (a[6]+a[7]));
        } else {
            int lp = 1 + (t >> 7);
            int row = t & 127;
            const float* b2l = b2 + (lp-1)*256;
            const float* wmrow = (row < 64) ? (Wsrc + (size_t)lp*16384 + row*256)
                                            : (Wdst + (size_t)lp*16384 + (row-64)*256);
            float acc = 0.f;
            #pragma unroll 8
            for (int c = 0; c < 256; ++c) acc += wmrow[c] * b2l[c];
            acc += (row < 64) ? bias1[lp*64 + row] : bias2[lp*64 + (row-64)];
            bcomb[(lp-1)*128 + row] = acc;
            if (t == 0) {
                float bo = 0.f;
                const float* b23 = b2 + 2*256;
                #pragma unroll 8
                for (int c = 0; c < 256; ++c) bo += Wfc[c] * b23[c];
                out[0] = bo + bfc[0];
            }
        }
        return;
    }
    // ================= MFMA table build (eproj-v3 body on 1024 grid rows; 16 blocks) =========
    {
        const int m0t = (blockIdx.x - 444) * 64;
        const float gamma = 31.875f;
        const float step  = 8.0f / 255.0f;
        const float step_t = TBL_DMAX / (float)(TBL_N - 1);
        float dv = (float)(m0t + w*16 + lr) * step_t;
        bf16x8 af[8];
        #pragma unroll
        for (int ks = 0; ks < 8; ++ks) {
            unsigned short h[8];
            int kb = ks*32 + lq*8;
            #pragma unroll
            for (int j = 0; j < 8; ++j) {
                float tt2 = dv - (float)(kb+j)*step;
                h[j] = f2b(__expf(-gamma*tt2*tt2));
            }
            af[ks] = *(bf16x8*)h;
        }
        const unsigned short* Bl = Bwp + lane*8;
        #pragma unroll
        for (int ct = 0; ct < 12; ++ct) {
            const unsigned short* Bb = Bl + (ct/3)*12288 + (ct%3)*4096;
            uint4 pb[8];
            #pragma unroll
            for (int ks = 0; ks < 8; ++ks)
                pb[ks] = *(const uint4*)(Bb + ks*512);
            floatx4 acc = {};
            #pragma unroll
            for (int ks = 0; ks < 8; ++ks)
                acc = __builtin_amdgcn_mfma_f32_16x16x32_bf16(
                    af[ks], *(const bf16x8*)&pb[ks], acc, 0, 0, 0);
            int bc = (ct/3)*48 + (ct%3)*16 + lr;
            float bv = bedge[bc];
            #pragma unroll
            for (int rg = 0; rg < 4; ++rg) {
                int row = m0t + w*16 + lq*4 + rg;
                T[(size_t)row*192 + bc] = f2b(acc[rg] + bv);
            }
        }
    }
}

// ---------------- fused FF + wcomb v2: out-col split (grid.y=2) + double-buffered s_h ----------
#define HP 72
__global__ __launch_bounds__(256) void ffw_kernel(
    const unsigned short* __restrict__ XN,   // [N,64] bf16
    const unsigned short* __restrict__ W1p,  // PACKED W1 frags (this layer)
    const float* __restrict__ b1l,           // [1024]
    const unsigned short* __restrict__ WCp,  // PACKED wcomb frags (this layer)
    const float* __restrict__ bcl,           // [128]
    unsigned short* __restrict__ XO,         // [N,128] bf16
    int M) {
    __shared__ __align__(16) unsigned short s_h[2][16*HP];  // double-buffered h chunk
    __shared__ __align__(16) unsigned short s_c[16*HP];     // epilogue [16][72] (64 cols used)
    const int t = threadIdx.x;
    const int wv = t >> 6, lane = t & 63, lr = lane & 15, lq = lane >> 4;
    const int m0 = blockIdx.x * 16;
    const int by = blockIdx.y;               // out-col half: cols by*64 .. +64

    int ga = m0 + lr;
    bool aok = ga < M;
    uint4 a0 = aok ? *(const uint4*)(XN + (size_t)ga*64 + lq*8) : make_uint4(0,0,0,0);
    uint4 a1 = aok ? *(const uint4*)(XN + (size_t)ga*64 + 32 + lq*8) : make_uint4(0,0,0,0);

    floatx4 acc2 = {};                       // 16 rows x 16 out-cols (this wave's tile)

    const unsigned short* W1b = W1p + (size_t)wv*1024 + lane*8;   // + f*4096 + j*512
    const int otl = by*4 + wv;
    const unsigned short* WCb = WCp + (size_t)(otl >> 1)*2048 + (size_t)(otl & 1)*1024 + lane*8;

    uint4 pb1[2], pb2[2];
    pb1[0] = *(const uint4*)(W1b);
    pb1[1] = *(const uint4*)(W1b + 512);
    pb2[0] = *(const uint4*)(WCb);
    pb2[1] = *(const uint4*)(WCb + 512);

    for (int f = 0; f < 16; ++f) {
        uint4 cb1_0 = pb1[0], cb1_1 = pb1[1];
        uint4 cb2_0 = pb2[0], cb2_1 = pb2[1];
        float bv1 = b1l[f*64 + wv*16 + lr];
        if (f < 15) {
            const unsigned short* n1 = W1b + (f+1)*4096;
            const unsigned short* n2 = WCb + (f+1)*8192;
            pb1[0] = *(const uint4*)(n1);
            pb1[1] = *(const uint4*)(n1 + 512);
            pb2[0] = *(const uint4*)(n2);
            pb2[1] = *(const uint4*)(n2 + 512);
        }
        floatx4 hacc = {};
        hacc = __builtin_amdgcn_mfma_f32_16x16x32_bf16(
            *(const bf16x8*)&a0, *(const bf16x8*)&cb1_0, hacc, 0,0,0);
        hacc = __builtin_amdgcn_mfma_f32_16x16x32_bf16(
            *(const bf16x8*)&a1, *(const bf16x8*)&cb1_1, hacc, 0,0,0);
        unsigned short* sh = s_h[f & 1];
        {
            int col = wv*16 + lr;
            #pragma unroll
            for (int rg = 0; rg < 4; ++rg) {
                int row = lq*4 + rg;
                sh[row*HP + col] = f2b(silu_f(hacc[rg] + bv1));
            }
        }
        __syncthreads();
        bf16x8 ha0 = *(const bf16x8*)(&sh[lr*HP + lq*8]);
        bf16x8 ha1 = *(const bf16x8*)(&sh[lr*HP + 32 + lq*8]);
        acc2 = __builtin_amdgcn_mfma_f32_16x16x32_bf16(ha0, *(const bf16x8*)&cb2_0, acc2, 0,0,0);
        acc2 = __builtin_amdgcn_mfma_f32_16x16x32_bf16(ha1, *(const bf16x8*)&cb2_1, acc2, 0,0,0);
    }

    {
        int col = wv*16 + lr;                // 0..63 within this half
        float bv = bcl[by*64 + col];
        #pragma unroll
        for (int rg = 0; rg < 4; ++rg) {
            int row = lq*4 + rg;
            s_c[row*HP + col] = f2b(acc2[rg] + bv);
        }
    }
    __syncthreads();
    if (t < 128) {
        int row = t >> 3, c8 = t & 7;        // 16 rows x 8 uint4 (64 cols)
        int gm = m0 + row;
        if (gm < M)
            *(uint4*)(XO + (size_t)gm*128 + by*64 + c8*8) = *(const uint4*)(s_c + row*HP + c8*8);
    }
}

// ---------------- layer-2 FF + fused final reduction (packed W1, barrier-free loop) ----------------
__global__ __launch_bounds__(256) void ffa_kernel(
    const unsigned short* __restrict__ XN,   // [N,64] bf16
    const unsigned short* __restrict__ W1p,  // PACKED W1 frags (layer 2)
    const float* __restrict__ b1l,           // [1024]
    const float* __restrict__ wfc2,          // [1024]
    float* __restrict__ out, int M) {
    __shared__ float red[256];
    const int t = threadIdx.x;
    const int wv = t >> 6, lane = t & 63, lr = lane & 15, lq = lane >> 4;
    const int m0 = blockIdx.x * 16;

    int ga = m0 + lr;
    bool aok = ga < M;
    uint4 a0 = aok ? *(const uint4*)(XN + (size_t)ga*64 + lq*8) : make_uint4(0,0,0,0);
    uint4 a1 = aok ? *(const uint4*)(XN + (size_t)ga*64 + 32 + lq*8) : make_uint4(0,0,0,0);

    const unsigned short* W1b = W1p + (size_t)wv*1024 + lane*8;
    uint4 pb0 = *(const uint4*)(W1b);
    uint4 pb1 = *(const uint4*)(W1b + 512);

    float partial = 0.f;
    for (int f = 0; f < 16; ++f) {
        uint4 c0 = pb0, c1 = pb1;
        if (f < 15) {
            pb0 = *(const uint4*)(W1b + (f+1)*4096);
            pb1 = *(const uint4*)(W1b + (f+1)*4096 + 512);
        }
        floatx4 hacc = {};
        hacc = __builtin_amdgcn_mfma_f32_16x16x32_bf16(
            *(const bf16x8*)&a0, *(const bf16x8*)&c0, hacc, 0,0,0);
        hacc = __builtin_amdgcn_mfma_f32_16x16x32_bf16(
            *(const bf16x8*)&a1, *(const bf16x8*)&c1, hacc, 0,0,0);
        float bv1 = b1l[f*64 + wv*16 + lr];
        float wvv = wfc2[f*64 + wv*16 + lr];
        #pragma unroll
        for (int rg = 0; rg < 4; ++rg) {
            int gm = m0 + lq*4 + rg;
            if (gm < M) partial += silu_f(hacc[rg] + bv1) * wvv;
        }
    }
    red[t] = partial;
    __syncthreads();
    for (int off = 128; off > 0; off >>= 1) {
        if (t < off) red[t] += red[t+off];
        __syncthreads();
    }
    if (t == 0) atomicAdd(out, red[0] * (1.0f/(float)N_NODES));
}

// ---------------- angle attention v6: split-k x4 logits (512 threads) + shuffle softmax --------
// Each (p,q) pair handled by 4 threads (quarters of k); quarter seeds T16/T17, T32/T33, T48/T49
// via Chebyshev doubling identities; partials combined with 2 shfl_xor. Serial chain ~halves.
__global__ __launch_bounds__(512) void angle_kernel(
    const unsigned short* __restrict__ xjxi,
    const unsigned short* __restrict__ T,    // [TBL_N,192] bf16 eproj table
    int lc0,                                 // layer col offset: 0/64/128
    const float* __restrict__ dvec,          // [E]
    const float* __restrict__ rhat,
    const int*   __restrict__ src,
    const float* __restrict__ attn,
    unsigned short* __restrict__ xn) {
    __shared__ __align__(16) float s_xij[16][68];
    __shared__ float s_rhat[16][4];
    __shared__ float s_logit[16][17];
    __shared__ float s_a[16][17];
    __shared__ float s_w[16];
    const int tt = threadIdx.x;
    const int node = blockIdx.x;

    if (tt < 16) {
        float4 rv = *(const float4*)(rhat + (size_t)(node*DEG_ + tt)*4);
        s_rhat[tt][0] = rv.x; s_rhat[tt][1] = rv.y; s_rhat[tt][2] = rv.z; s_rhat[tt][3] = 0.f;
        s_logit[tt][tt] = -1e30f;      // diag -> exp() == 0
    }
    if (tt < 256) {
        int p = tt >> 4, c4 = tt & 15;    // 256 threads: 16 edges x 16 chunks of 4 elems
        int e = node*DEG_ + p;
        int se = src[e];
        ushort4 aj = *(const ushort4*)(xjxi + (size_t)se*128 + c4*4);
        ushort4 ai = *(const ushort4*)(xjxi + (size_t)node*128 + 64 + c4*4);
        const float inv_step_t = (float)(TBL_N - 1) / TBL_DMAX;
        float u = fminf(dvec[e] * inv_step_t, (float)(TBL_N - 2) + 0.999f);
        int i0 = (int)u;
        float fr = u - (float)i0;
        const unsigned short* t0 = T + (size_t)i0*192 + lc0 + c4*4;
        ushort4 w0 = *(const ushort4*)t0;
        ushort4 w1 = *(const ushort4*)(t0 + 192);
        float v0x = b2f(w0.x), v0y = b2f(w0.y), v0z = b2f(w0.z), v0w = b2f(w0.w);
        s_xij[p][c4*4+0] = b2f(aj.x) + b2f(ai.x) + fmaf(fr, b2f(w1.x) - v0x, v0x);
        s_xij[p][c4*4+1] = b2f(aj.y) + b2f(ai.y) + fmaf(fr, b2f(w1.y) - v0y, v0y);
        s_xij[p][c4*4+2] = b2f(aj.z) + b2f(ai.z) + fmaf(fr, b2f(w1.z) - v0z, v0z);
        s_xij[p][c4*4+3] = b2f(aj.w) + b2f(ai.w) + fmaf(fr, b2f(w1.w) - v0w, v0w);
    }
    __syncthreads();
    int pp = 0, qq = 0;
    float lg = 0.f;
    if (tt < 480) {
        int pair = tt >> 2, quad = tt & 3;
        pp = (int)((1.0f + sqrtf(8.0f*(float)pair + 1.0f)) * 0.5f);
        qq = pair - ((pp*(pp-1)) >> 1);
        float c = s_rhat[pp][0]*s_rhat[qq][0] + s_rhat[pp][1]*s_rhat[qq][1]
                + s_rhat[pp][2]*s_rhat[qq][2];
        c = fminf(fmaxf(c, -0.999999f), 0.999999f);
        float c2 = 2.0f * c;
        // Chebyshev doubling seeds (verified identities):
        float T2  = fmaf(c2, c, -1.0f);
        float T3  = fmaf(2.0f*T2,  c,   -c);
        float T4  = fmaf(2.0f*T2,  T2,  -1.0f);
        float T7  = fmaf(2.0f*T4,  T3,  -c);
        float T8  = fmaf(2.0f*T4,  T4,  -1.0f);
        float T15 = fmaf(2.0f*T8,  T7,  -c);
        float T16 = fmaf(2.0f*T8,  T8,  -1.0f);
        float T17 = fmaf(2.0f*T16, c,   -T15);
        float T31 = fmaf(2.0f*T16, T15, -c);
        float T32 = fmaf(2.0f*T16, T16, -1.0f);
        float T33 = fmaf(2.0f*T32, c,   -T31);
        float T47 = fmaf(2.0f*T32, T15, -T17);
        float T48 = fmaf(2.0f*T32, T16, -T16);
        float T49 = fmaf(2.0f*T48, c,   -T47);
        float tk0, tk1;
        if      (quad == 0) { tk0 = 1.0f; tk1 = c;   }
        else if (quad == 1) { tk0 = T16;  tk1 = T17; }
        else if (quad == 2) { tk0 = T32;  tk1 = T33; }
        else                { tk0 = T48;  tk1 = T49; }
        const float* xp = &s_xij[pp][0] + quad*16;
        const float* xq = &s_xij[qq][0] + quad*16;
        const float* at = attn + quad*16;
        float acc = 0.f;
        #pragma unroll
        for (int k0 = 0; k0 < 16; k0 += 4) {
            float4 xp4 = *(const float4*)(xp + k0);
            float4 xq4 = *(const float4*)(xq + k0);
            float a0 = at[k0+0], a1 = at[k0+1], a2 = at[k0+2], a3 = at[k0+3];
            float v0 = tk0 + xp4.x + xq4.x;
            acc = fmaf(a0, silu_f(v0), acc);
            { float tn2 = c2*tk1 - tk0; tk0 = tk1; tk1 = tn2; }
            float v1 = tk0 + xp4.y + xq4.y;
            acc = fmaf(a1, silu_f(v1), acc);
            { float tn2 = c2*tk1 - tk0; tk0 = tk1; tk1 = tn2; }
            float v2 = tk0 + xp4.z + xq4.z;
            acc = fmaf(a2, silu_f(v2), acc);
            { float tn2 = c2*tk1 - tk0; tk0 = tk1; tk1 = tn2; }
            float v3 = tk0 + xp4.w + xq4.w;
            acc = fmaf(a3, silu_f(v3), acc);
            { float tn2 = c2*tk1 - tk0; tk0 = tk1; tk1 = tn2; }
        }
        lg = acc;
    }
    lg += __shfl_xor(lg, 1);
    lg += __shfl_xor(lg, 2);
    if (tt < 480 && (tt & 3) == 0) {
        s_logit[pp][qq] = lg;
        s_logit[qq][pp] = lg;
    }
    __syncthreads();
    // column softmax: thread (q = tt>>4, p = tt&15); shfl groups of 16 share q
    if (tt < 256) {
        int q = tt >> 4, p = tt & 15;
        float l = s_logit[p][q];
        float m = l;
        m = fmaxf(m, __shfl_xor(m, 1));
        m = fmaxf(m, __shfl_xor(m, 2));
        m = fmaxf(m, __shfl_xor(m, 4));
        m = fmaxf(m, __shfl_xor(m, 8));
        float e = __expf(l - m);
        float z = e;
        z += __shfl_xor(z, 1);
        z += __shfl_xor(z, 2);
        z += __shfl_xor(z, 4);
        z += __shfl_xor(z, 8);
        s_a[p][q] = e * __builtin_amdgcn_rcpf(z);   // attention weight, zi folded in
    }
    __syncthreads();
    // row-sum: thread (p = tt>>4, q = tt&15); sw[p] = sum_q a[p][q]
    if (tt < 256) {
        int p = tt >> 4, q = tt & 15;
        float a = s_a[p][q];
        a += __shfl_xor(a, 1);
        a += __shfl_xor(a, 2);
        a += __shfl_xor(a, 4);
        a += __shfl_xor(a, 8);
        if (q == 0) s_w[p] = a;
    }
    __syncthreads();
    if (tt < 64) {
        float acc = 0.f;
        #pragma unroll
        for (int p = 0; p < 16; ++p) acc += s_w[p] * s_xij[p][tt];
        xn[(size_t)node*64 + tt] = f2b(acc);
    }
}

extern "C" void kernel_launch(void* const* d_in, const int* in_sizes, int n_in,
                              void* d_out, int out_size, void* d_ws, size_t ws_size,
                              hipStream_t stream) {
    (void)in_sizes; (void)n_in; (void)out_size; (void)ws_size;
    const float* r    = (const float*)d_in[0];
    const int*   an   = (const int*)  d_in[1];
    const int*   src  = (const int*)  d_in[2];
    const float* emb  = (const float*)d_in[6];
    const float* Wsrc = (const float*)d_in[7];
    const float* bsrc = (const float*)d_in[8];
    const float* Wdst = (const float*)d_in[9];
    const float* bdst = (const float*)d_in[10];
    const float* Wedge= (const float*)d_in[11];
    const float* bedge= (const float*)d_in[12];
    const float* attn = (const float*)d_in[13];
    const float* W1   = (const float*)d_in[14];
    const float* b1   = (const float*)d_in[15];
    const float* W2   = (const float*)d_in[16];
    const float* b2   = (const float*)d_in[17];
    const float* Wfc  = (const float*)d_in[18];
    const float* bfc  = (const float*)d_in[19];

    char* ws = (char*)d_ws;
    float* d_d              = (float*)(ws);                    // 384000 B
    float* d_rhat           = (float*)(ws + 384000);           // 1536000 B
    unsigned short* d_wsdp  = (unsigned short*)(ws + 1920000); // 65536 B (packed wsrc/wdst)
    unsigned short* d_wedgep= (unsigned short*)(ws + 1985536); // 98304 B (packed Wedge)
    unsigned short* d_xjxi  = (unsigned short*)(ws + 7252992); // 1536000 B
    unsigned short* d_table = (unsigned short*)(ws + 8788992); // 393216 B (bf16 eproj table)
    unsigned short* d_xn    = (unsigned short*)(ws + 45652992);// 768000 B
    unsigned short* d_wcomb = (unsigned short*)(ws + 46420992);// 524288 B (packed)
    float* d_bcomb          = (float*)(ws + 46945280);         // 1024 B
    float* d_wfc2           = (float*)(ws + 46946304);         // 4096 B
    unsigned short* d_w1p   = (unsigned short*)(ws + 47048704);// 393216 B (packed, 3 layers)
    float* out = (float*)d_out;

    // prep: pure streaming branches, no LDS (embed relay removed)
    prep_kernel<<<GEOM_BLOCKS + WPACK1_BLOCKS + WSDP_BLOCKS + WPACKE_BLOCKS,
                  256, 0, stream>>>(
        Wsrc, Wdst, W1, Wedge, r, d_d, d_rhat, d_w1p, d_wsdp, d_wedgep);

    // merged gemm0 (fused embed) [0,375) + wcomb [375,444) + MFMA table build [444,460)
    eplg_kernel<<<375 + 69 + 16, 256, 0, stream>>>(
        an, emb, d_wsdp, bsrc, bdst, d_xjxi,
        Wsrc, Wdst, W2, b2, Wfc, bfc,
        d_wcomb, d_bcomb, d_wfc2,
        d_wedgep, bedge, d_table, out);

    // ---- layer 0 ----
    angle_kernel<<<N_NODES, 512, 0, stream>>>(
        d_xjxi, d_table, 0, d_d, d_rhat, src, attn, d_xn);
    ffw_kernel<<<dim3(375, 2), 256, 0, stream>>>(
        d_xn, d_w1p, b1, d_wcomb, d_bcomb, d_xjxi, N_NODES);

    // ---- layer 1 ----
    angle_kernel<<<N_NODES, 512, 0, stream>>>(
        d_xjxi, d_table, 64, d_d, d_rhat, src, attn + 64, d_xn);
    ffw_kernel<<<dim3(375, 2), 256, 0, stream>>>(
        d_xn, d_w1p + 65536, b1 + 1024, d_wcomb + 131072, d_bcomb + 128, d_xjxi, N_NODES);

    // ---- layer 2 (FF + final reduction, packed W1, barrier-free loop) ----
    angle_kernel<<<N_NODES, 512, 0, stream>>>(
        d_xjxi, d_table, 128, d_d, d_rhat, src, attn + 128, d_xn);
    ffa_kernel<<<375, 256, 0, stream>>>(
        d_xn, d_w1p + 131072, b1 + 2048, d_wfc2, out, N_NODES);
}

// Round 20
// 217.174 us; speedup vs baseline: 1.0779x; 1.0779x over previous
//
#include <hip/hip_runtime.h>

#define N_NODES 6000
#define DEG_    16
#define N_EDGES (N_NODES*DEG_)
#define D_MODEL 256
#define D_MSG   64
#define D_FF    1024

#define TBL_N   1024
#define TBL_DMAX 9.0f

typedef __bf16 bf16x8 __attribute__((ext_vector_type(8)));
typedef float floatx4 __attribute__((ext_vector_type(4)));

__device__ __forceinline__ float silu_f(float v) {
    return v * __builtin_amdgcn_rcpf(1.0f + __expf(-v));
}
__device__ __forceinline__ float b2f(unsigned short u) {
    union { unsigned int i; float f; } v; v.i = ((unsigned int)u) << 16; return v.f;
}
__device__ __forceinline__ unsigned short f2b(float f) {
    union { float f; unsigned int i; } v; v.f = f;
    unsigned int r = (v.i + 0x7FFFu + ((v.i >> 16) & 1u)) >> 16;
    return (unsigned short)r;
}

// ---------------- prep: geom + W1 pack + wsrc/wdst pack + Wedge pack (no embed relay) ----------
#define GEOM_BLOCKS (N_EDGES/256)              // 375
#define WPACK1_BLOCKS 96                       // W1 pack (3 layers): 24576 lane-frags
#define WSDP_BLOCKS 16                         // wsrc/wdst pack: 4096 lane-frags
#define WPACKE_BLOCKS 24                       // Wedge pack: 6144 lane-frags
__global__ __launch_bounds__(256) void prep_kernel(
    const float* __restrict__ Wsrc, const float* __restrict__ Wdst,
    const float* __restrict__ W1, const float* __restrict__ Wedge,
    const float* __restrict__ r, float* __restrict__ d, float* __restrict__ rhat,
    unsigned short* __restrict__ w1p,        // PACKED [3 layers][8192 frags][8]
    unsigned short* __restrict__ wsdp,       // PACKED [8 tiles][8 ks][64 lane][8]
    unsigned short* __restrict__ wedgep) {   // PACKED [6144 frags][8]
    int b = blockIdx.x;
    int t = threadIdx.x;
    if (b < GEOM_BLOCKS) {
        int e = b*256 + t;
        float xx = r[e*3+0], yy = r[e*3+1], zz = r[e*3+2];
        float n = sqrtf(xx*xx + yy*yy + zz*zz);
        d[e] = n;
        float inv = 1.0f / n;
        *(float4*)(rhat + (size_t)e*4) = make_float4(xx*inv, yy*inv, zz*inv, 0.f);
    } else if (b < GEOM_BLOCKS + WPACK1_BLOCKS) {
        // W1 fragment pack (3 layers): i2 = lp*8192 + f*512 + wv*128 + j*64 + lane
        int wb = b - GEOM_BLOCKS;
        int i2 = wb*256 + t;                 // 0..24575
        int lp = i2 >> 13;                   // 0..2
        int e = i2 & 8191;
        int lane = e & 63, j = (e >> 6) & 1, wv = (e >> 7) & 3, f = e >> 9;
        int row = f*64 + wv*16 + (lane & 15);
        int col = j*32 + (lane >> 4)*8;
        const float* sp = W1 + (size_t)lp*65536 + (size_t)row*64 + col;
        float4 v0 = *(const float4*)sp;
        float4 v1 = *(const float4*)(sp + 4);
        unsigned short h[8] = { f2b(v0.x), f2b(v0.y), f2b(v0.z), f2b(v0.w),
                                f2b(v1.x), f2b(v1.y), f2b(v1.z), f2b(v1.w) };
        *(uint4*)(w1p + (size_t)i2*8) = *(uint4*)h;
    } else if (b < GEOM_BLOCKS + WPACK1_BLOCKS + WSDP_BLOCKS) {
        // wsrc/wdst fragment pack (layer 0): i = tl*512 + ks*64 + lane, tl = bx*4+ns
        int wb = b - (GEOM_BLOCKS + WPACK1_BLOCKS);
        int i = wb*256 + t;                  // 0..4095
        int lane = i & 63, ks = (i >> 6) & 7, tl = i >> 9;   // tl 0..7
        int bx = tl >> 2, ns = tl & 3;
        int row = ns*16 + (lane & 15);
        int col = ks*32 + (lane >> 4)*8;
        const float* sp = (bx ? Wdst : Wsrc) + (size_t)row*256 + col;
        float4 v0 = *(const float4*)sp;
        float4 v1 = *(const float4*)(sp + 4);
        unsigned short h[8] = { f2b(v0.x), f2b(v0.y), f2b(v0.z), f2b(v0.w),
                                f2b(v1.x), f2b(v1.y), f2b(v1.z), f2b(v1.w) };
        *(uint4*)(wsdp + (size_t)i*8) = *(uint4*)h;
    } else {
        // Wedge fragment pack: i = ((w*3+ns)*8+ks)*64 + lane, i in [0,6144)
        int wb = b - (GEOM_BLOCKS + WPACK1_BLOCKS + WSDP_BLOCKS);
        int i = wb*256 + t;                  // 0..6143
        int lane = i & 63, ks = (i >> 6) & 7, rem = i >> 9;   // rem 0..11
        int ns = rem % 3, w = rem / 3;                        // w 0..3
        int row = 48*w + ns*16 + (lane & 15);
        int col = ks*32 + (lane >> 4)*8;
        const float* sp = Wedge + (size_t)row*256 + col;
        float4 v0 = *(const float4*)sp;
        float4 v1 = *(const float4*)(sp + 4);
        unsigned short h[8] = { f2b(v0.x), f2b(v0.y), f2b(v0.z), f2b(v0.w),
                                f2b(v1.x), f2b(v1.y), f2b(v1.z), f2b(v1.w) };
        *(uint4*)(wedgep + (size_t)i*8) = *(uint4*)h;
    }
}

// ---------------- merged: gemm0 [0,375) + wcomb/wfc2/bcomb [375,444) + MFMA table [444,460) ----
// gemm0 v3: embedding gather fused -- A fragments read straight from fp32 emb[an[row]],
// converted in-register (d_x relay buffer eliminated).
__global__ __launch_bounds__(256) void eplg_kernel(
    const int* __restrict__ an, const float* __restrict__ emb,
    const unsigned short* __restrict__ wsdp, // PACKED wsrc/wdst frags
    const float* __restrict__ bias1,         // bsrc
    const float* __restrict__ bias2,         // bdst
    unsigned short* __restrict__ Cg,         // d_xjxi [N,128]
    const float* __restrict__ Wsrc, const float* __restrict__ Wdst,
    const float* __restrict__ W2, const float* __restrict__ b2,
    const float* __restrict__ Wfc, const float* __restrict__ bfc,
    unsigned short* __restrict__ wcomb,      // PACKED [2 layers][16384 frags][8]
    float* __restrict__ bcomb,
    float* __restrict__ wfc2,
    const unsigned short* __restrict__ Bwp,  // PACKED Wedge frags
    const float* __restrict__ bedge,         // [192]
    unsigned short* __restrict__ T,          // [TBL_N,192] bf16 out
    float* __restrict__ out) {
    const int t = threadIdx.x;
    const int w = t >> 6, lane = t & 63, lr = lane & 15, lq = lane >> 4;

    if (blockIdx.x < 375) {
        // ================= layer0 GEMM, barrier-free, fused embed gather =================
        const int m0 = blockIdx.x * 16;
        const float* erow = emb + (size_t)an[m0 + lr]*D_MODEL;
        bf16x8 af[8];
        #pragma unroll
        for (int ks = 0; ks < 8; ++ks) {
            float4 v0 = *(const float4*)(erow + ks*32 + lq*8);
            float4 v1 = *(const float4*)(erow + ks*32 + lq*8 + 4);
            unsigned short h[8] = { f2b(v0.x), f2b(v0.y), f2b(v0.z), f2b(v0.w),
                                    f2b(v1.x), f2b(v1.y), f2b(v1.z), f2b(v1.w) };
            af[ks] = *(bf16x8*)h;
        }
        #pragma unroll
        for (int h = 0; h < 2; ++h) {
            int tl = w*2 + h;                // 0..7
            int bx = tl >> 2, ns = tl & 3;
            const unsigned short* pbase = wsdp + ((size_t)tl*512 + lane)*8;
            uint4 pb[8];
            #pragma unroll
            for (int ks = 0; ks < 8; ++ks)
                pb[ks] = *(const uint4*)(pbase + ks*512);
            floatx4 acc = {};
            #pragma unroll
            for (int ks = 0; ks < 8; ++ks)
                acc = __builtin_amdgcn_mfma_f32_16x16x32_bf16(
                    af[ks], *(const bf16x8*)&pb[ks], acc, 0, 0, 0);
            int col = bx*64 + ns*16 + lr;
            float bv = (bx ? bias2 : bias1)[ns*16 + lr];
            #pragma unroll
            for (int rg = 0; rg < 4; ++rg) {
                int gm = m0 + lq*4 + rg;
                Cg[(size_t)gm*128 + col] = f2b(acc[rg] + bv);
            }
        }
        return;
    }
    if (blockIdx.x < 444) {
        // ================= wcomb/wfc2/bcomb branch =================
        int b = blockIdx.x - 375;        // 0..68
        if (b < 64) {
            int lp  = 1 + (b >> 5);      // layer index 1,2
            int wb2 = b & 31;            // 32 blocks/layer
            const float* W2f = W2 + (size_t)(lp-1)*262144;
            const float* wm[4];
            #pragma unroll
            for (int i = 0; i < 4; ++i) {
                int row = wb2*4 + i;
                wm[i] = (row < 64) ? (Wsrc + (size_t)lp*16384 + row*256)
                                   : (Wdst + (size_t)lp*16384 + (row-64)*256);
            }
            float acc[4][4] = {};
            int c0 = t*4;
            #pragma unroll 8
            for (int c = 0; c < 256; ++c) {
                float4 w2v = *(const float4*)(W2f + (size_t)c*1024 + c0);
                #pragma unroll
                for (int i = 0; i < 4; ++i) {
                    float wv2 = wm[i][c];
                    acc[i][0] = fmaf(wv2, w2v.x, acc[i][0]);
                    acc[i][1] = fmaf(wv2, w2v.y, acc[i][1]);
                    acc[i][2] = fmaf(wv2, w2v.z, acc[i][2]);
                    acc[i][3] = fmaf(wv2, w2v.w, acc[i][3]);
                }
            }
            int fc = t >> 4, j = (t >> 3) & 1, lq2 = (t >> 1) & 3, cpos = (t & 1) * 4;
            #pragma unroll
            for (int i = 0; i < 4; ++i) {
                int row = wb2*4 + i;
                int wv2 = row >> 5, ns = (row >> 4) & 1, lr2 = row & 15;
                *(ushort4*)(wcomb + (size_t)(lp-1)*131072
                            + (size_t)fc*8192 + wv2*2048 + ns*1024 + j*512 + (lq2*16+lr2)*8 + cpos) =
                    make_ushort4(f2b(acc[i][0]), f2b(acc[i][1]), f2b(acc[i][2]), f2b(acc[i][3]));
            }
        } else if (b < 68) {
            int c = (b - 64)*256 + t;
            const float* W2f = W2 + 2*262144;
            float a[8] = {};
            #pragma unroll 4
            for (int k = 0; k < 256; k += 8) {
                #pragma unroll
                for (int j = 0; j < 8; ++j)
                    a[j] = fmaf(Wfc[k+j], W2f[(size_t)(k+j)*1024 + c], a[j]);
            }
            wfc2[c] = ((a[0]+a[1]) + (a[2]+a[3])) + ((a[4]+a[5]) + (a[6]+a[7]));
        } else {
            int lp = 1 + (t >> 7);
            int row = t & 127;
            const float* b2l = b2 + (lp-1)*256;
            const float* wmrow = (row < 64) ? (Wsrc + (size_t)lp*16384 + row*256)
                                            : (Wdst + (size_t)lp*16384 + (row-64)*256);
            float acc = 0.f;
            #pragma unroll 8
            for (int c = 0; c < 256; ++c) acc += wmrow[c] * b2l[c];
            acc += (row < 64) ? bias1[lp*64 + row] : bias2[lp*64 + (row-64)];
            bcomb[(lp-1)*128 + row] = acc;
            if (t == 0) {
                float bo = 0.f;
                const float* b23 = b2 + 2*256;
                #pragma unroll 8
                for (int c = 0; c < 256; ++c) bo += Wfc[c] * b23[c];
                out[0] = bo + bfc[0];
            }
        }
        return;
    }
    // ================= MFMA table build (eproj-v3 body on 1024 grid rows; 16 blocks) =========
    {
        const int m0t = (blockIdx.x - 444) * 64;
        const float gamma = 31.875f;
        const float step  = 8.0f / 255.0f;
        const float step_t = TBL_DMAX / (float)(TBL_N - 1);
        float dv = (float)(m0t + w*16 + lr) * step_t;
        bf16x8 af[8];
        #pragma unroll
        for (int ks = 0; ks < 8; ++ks) {
            unsigned short h[8];
            int kb = ks*32 + lq*8;
            #pragma unroll
            for (int j = 0; j < 8; ++j) {
                float tt2 = dv - (float)(kb+j)*step;
                h[j] = f2b(__expf(-gamma*tt2*tt2));
            }
            af[ks] = *(bf16x8*)h;
        }
        const unsigned short* Bl = Bwp + lane*8;
        #pragma unroll
        for (int ct = 0; ct < 12; ++ct) {
            const unsigned short* Bb = Bl + (ct/3)*12288 + (ct%3)*4096;
            uint4 pb[8];
            #pragma unroll
            for (int ks = 0; ks < 8; ++ks)
                pb[ks] = *(const uint4*)(Bb + ks*512);
            floatx4 acc = {};
            #pragma unroll
            for (int ks = 0; ks < 8; ++ks)
                acc = __builtin_amdgcn_mfma_f32_16x16x32_bf16(
                    af[ks], *(const bf16x8*)&pb[ks], acc, 0, 0, 0);
            int bc = (ct/3)*48 + (ct%3)*16 + lr;
            float bv = bedge[bc];
            #pragma unroll
            for (int rg = 0; rg < 4; ++rg) {
                int row = m0t + w*16 + lq*4 + rg;
                T[(size_t)row*192 + bc] = f2b(acc[rg] + bv);
            }
        }
    }
}

// ---------------- fused FF + wcomb v2: out-col split (grid.y=2) + double-buffered s_h ----------
#define HP 72
__global__ __launch_bounds__(256) void ffw_kernel(
    const unsigned short* __restrict__ XN,   // [N,64] bf16
    const unsigned short* __restrict__ W1p,  // PACKED W1 frags (this layer)
    const float* __restrict__ b1l,           // [1024]
    const unsigned short* __restrict__ WCp,  // PACKED wcomb frags (this layer)
    const float* __restrict__ bcl,           // [128]
    unsigned short* __restrict__ XO,         // [N,128] bf16
    int M) {
    __shared__ __align__(16) unsigned short s_h[2][16*HP];  // double-buffered h chunk
    __shared__ __align__(16) unsigned short s_c[16*HP];     // epilogue [16][72] (64 cols used)
    const int t = threadIdx.x;
    const int wv = t >> 6, lane = t & 63, lr = lane & 15, lq = lane >> 4;
    const int m0 = blockIdx.x * 16;
    const int by = blockIdx.y;               // out-col half: cols by*64 .. +64

    int ga = m0 + lr;
    bool aok = ga < M;
    uint4 a0 = aok ? *(const uint4*)(XN + (size_t)ga*64 + lq*8) : make_uint4(0,0,0,0);
    uint4 a1 = aok ? *(const uint4*)(XN + (size_t)ga*64 + 32 + lq*8) : make_uint4(0,0,0,0);

    floatx4 acc2 = {};                       // 16 rows x 16 out-cols (this wave's tile)

    const unsigned short* W1b = W1p + (size_t)wv*1024 + lane*8;   // + f*4096 + j*512
    const int otl = by*4 + wv;
    const unsigned short* WCb = WCp + (size_t)(otl >> 1)*2048 + (size_t)(otl & 1)*1024 + lane*8;

    uint4 pb1[2], pb2[2];
    pb1[0] = *(const uint4*)(W1b);
    pb1[1] = *(const uint4*)(W1b + 512);
    pb2[0] = *(const uint4*)(WCb);
    pb2[1] = *(const uint4*)(WCb + 512);

    for (int f = 0; f < 16; ++f) {
        uint4 cb1_0 = pb1[0], cb1_1 = pb1[1];
        uint4 cb2_0 = pb2[0], cb2_1 = pb2[1];
        float bv1 = b1l[f*64 + wv*16 + lr];
        if (f < 15) {
            const unsigned short* n1 = W1b + (f+1)*4096;
            const unsigned short* n2 = WCb + (f+1)*8192;
            pb1[0] = *(const uint4*)(n1);
            pb1[1] = *(const uint4*)(n1 + 512);
            pb2[0] = *(const uint4*)(n2);
            pb2[1] = *(const uint4*)(n2 + 512);
        }
        floatx4 hacc = {};
        hacc = __builtin_amdgcn_mfma_f32_16x16x32_bf16(
            *(const bf16x8*)&a0, *(const bf16x8*)&cb1_0, hacc, 0,0,0);
        hacc = __builtin_amdgcn_mfma_f32_16x16x32_bf16(
            *(const bf16x8*)&a1, *(const bf16x8*)&cb1_1, hacc, 0,0,0);
        unsigned short* sh = s_h[f & 1];
        {
            int col = wv*16 + lr;
            #pragma unroll
            for (int rg = 0; rg < 4; ++rg) {
                int row = lq*4 + rg;
                sh[row*HP + col] = f2b(silu_f(hacc[rg] + bv1));
            }
        }
        __syncthreads();
        bf16x8 ha0 = *(const bf16x8*)(&sh[lr*HP + lq*8]);
        bf16x8 ha1 = *(const bf16x8*)(&sh[lr*HP + 32 + lq*8]);
        acc2 = __builtin_amdgcn_mfma_f32_16x16x32_bf16(ha0, *(const bf16x8*)&cb2_0, acc2, 0,0,0);
        acc2 = __builtin_amdgcn_mfma_f32_16x16x32_bf16(ha1, *(const bf16x8*)&cb2_1, acc2, 0,0,0);
    }

    {
        int col = wv*16 + lr;                // 0..63 within this half
        float bv = bcl[by*64 + col];
        #pragma unroll
        for (int rg = 0; rg < 4; ++rg) {
            int row = lq*4 + rg;
            s_c[row*HP + col] = f2b(acc2[rg] + bv);
        }
    }
    __syncthreads();
    if (t < 128) {
        int row = t >> 3, c8 = t & 7;        // 16 rows x 8 uint4 (64 cols)
        int gm = m0 + row;
        if (gm < M)
            *(uint4*)(XO + (size_t)gm*128 + by*64 + c8*8) = *(const uint4*)(s_c + row*HP + c8*8);
    }
}

// ---------------- layer-2 FF + fused final reduction (packed W1, barrier-free loop) ----------------
__global__ __launch_bounds__(256) void ffa_kernel(
    const unsigned short* __restrict__ XN,   // [N,64] bf16
    const unsigned short* __restrict__ W1p,  // PACKED W1 frags (layer 2)
    const float* __restrict__ b1l,           // [1024]
    const float* __restrict__ wfc2,          // [1024]
    float* __restrict__ out, int M) {
    __shared__ float red[256];
    const int t = threadIdx.x;
    const int wv = t >> 6, lane = t & 63, lr = lane & 15, lq = lane >> 4;
    const int m0 = blockIdx.x * 16;

    int ga = m0 + lr;
    bool aok = ga < M;
    uint4 a0 = aok ? *(const uint4*)(XN + (size_t)ga*64 + lq*8) : make_uint4(0,0,0,0);
    uint4 a1 = aok ? *(const uint4*)(XN + (size_t)ga*64 + 32 + lq*8) : make_uint4(0,0,0,0);

    const unsigned short* W1b = W1p + (size_t)wv*1024 + lane*8;
    uint4 pb0 = *(const uint4*)(W1b);
    uint4 pb1 = *(const uint4*)(W1b + 512);

    float partial = 0.f;
    for (int f = 0; f < 16; ++f) {
        uint4 c0 = pb0, c1 = pb1;
        if (f < 15) {
            pb0 = *(const uint4*)(W1b + (f+1)*4096);
            pb1 = *(const uint4*)(W1b + (f+1)*4096 + 512);
        }
        floatx4 hacc = {};
        hacc = __builtin_amdgcn_mfma_f32_16x16x32_bf16(
            *(const bf16x8*)&a0, *(const bf16x8*)&c0, hacc, 0,0,0);
        hacc = __builtin_amdgcn_mfma_f32_16x16x32_bf16(
            *(const bf16x8*)&a1, *(const bf16x8*)&c1, hacc, 0,0,0);
        float bv1 = b1l[f*64 + wv*16 + lr];
        float wvv = wfc2[f*64 + wv*16 + lr];
        #pragma unroll
        for (int rg = 0; rg < 4; ++rg) {
            int gm = m0 + lq*4 + rg;
            if (gm < M) partial += silu_f(hacc[rg] + bv1) * wvv;
        }
    }
    red[t] = partial;
    __syncthreads();
    for (int off = 128; off > 0; off >>= 1) {
        if (t < off) red[t] += red[t+off];
        __syncthreads();
    }
    if (t == 0) atomicAdd(out, red[0] * (1.0f/(float)N_NODES));
}

// ---------------- angle attention: bf16-table lerp + split-k x2 logits + shuffle softmax -------
__global__ __launch_bounds__(256) void angle_kernel(
    const unsigned short* __restrict__ xjxi,
    const unsigned short* __restrict__ T,    // [TBL_N,192] bf16 eproj table
    int lc0,                                 // layer col offset: 0/64/128
    const float* __restrict__ dvec,          // [E]
    const float* __restrict__ rhat,
    const int*   __restrict__ src,
    const float* __restrict__ attn,
    unsigned short* __restrict__ xn) {
    __shared__ __align__(16) float s_xij[16][68];
    __shared__ float s_rhat[16][4];
    __shared__ float s_logit[16][17];
    __shared__ float s_a[16][17];
    __shared__ float s_w[16];
    const int tt = threadIdx.x;
    const int node = blockIdx.x;

    if (tt < 16) {
        float4 rv = *(const float4*)(rhat + (size_t)(node*DEG_ + tt)*4);
        s_rhat[tt][0] = rv.x; s_rhat[tt][1] = rv.y; s_rhat[tt][2] = rv.z; s_rhat[tt][3] = 0.f;
        s_logit[tt][tt] = -1e30f;      // diag -> exp() == 0
    }
    {
        int p = tt >> 4, c4 = tt & 15;    // 256 threads: 16 edges x 16 chunks of 4 elems
        int e = node*DEG_ + p;
        int se = src[e];
        ushort4 aj = *(const ushort4*)(xjxi + (size_t)se*128 + c4*4);
        ushort4 ai = *(const ushort4*)(xjxi + (size_t)node*128 + 64 + c4*4);
        const float inv_step_t = (float)(TBL_N - 1) / TBL_DMAX;
        float u = fminf(dvec[e] * inv_step_t, (float)(TBL_N - 2) + 0.999f);
        int i0 = (int)u;
        float fr = u - (float)i0;
        const unsigned short* t0 = T + (size_t)i0*192 + lc0 + c4*4;
        ushort4 w0 = *(const ushort4*)t0;
        ushort4 w1 = *(const ushort4*)(t0 + 192);
        float v0x = b2f(w0.x), v0y = b2f(w0.y), v0z = b2f(w0.z), v0w = b2f(w0.w);
        s_xij[p][c4*4+0] = b2f(aj.x) + b2f(ai.x) + fmaf(fr, b2f(w1.x) - v0x, v0x);
        s_xij[p][c4*4+1] = b2f(aj.y) + b2f(ai.y) + fmaf(fr, b2f(w1.y) - v0y, v0y);
        s_xij[p][c4*4+2] = b2f(aj.z) + b2f(ai.z) + fmaf(fr, b2f(w1.z) - v0z, v0z);
        s_xij[p][c4*4+3] = b2f(aj.w) + b2f(ai.w) + fmaf(fr, b2f(w1.w) - v0w, v0w);
    }
    __syncthreads();
    int pp = 0, qq = 0;
    float lg = 0.f;
    if (tt < 240) {
        int pair = tt >> 1, half = tt & 1;
        pp = (int)((1.0f + sqrtf(8.0f*(float)pair + 1.0f)) * 0.5f);
        qq = pair - ((pp*(pp-1)) >> 1);
        float c = s_rhat[pp][0]*s_rhat[qq][0] + s_rhat[pp][1]*s_rhat[qq][1]
                + s_rhat[pp][2]*s_rhat[qq][2];
        c = fminf(fmaxf(c, -0.999999f), 0.999999f);
        float c2 = 2.0f * c;
        float tk0, tk1;
        if (half) {
            float T2  = fmaf(c2, c, -1.0f);
            float T3  = fmaf(2.0f*T2,  c,   -c);
            float T4  = fmaf(2.0f*T2,  T2,  -1.0f);
            float T7  = fmaf(2.0f*T4,  T3,  -c);
            float T8  = fmaf(2.0f*T4,  T4,  -1.0f);
            float T15 = fmaf(2.0f*T8,  T7,  -c);
            float T16 = fmaf(2.0f*T8,  T8,  -1.0f);
            float T31 = fmaf(2.0f*T16, T15, -c);
            float T32 = fmaf(2.0f*T16, T16, -1.0f);
            float T33 = fmaf(2.0f*T32, c,   -T31);
            tk0 = T32; tk1 = T33;
        } else {
            tk0 = 1.0f; tk1 = c;
        }
        const float* xp = &s_xij[pp][0] + half*32;
        const float* xq = &s_xij[qq][0] + half*32;
        const float* at = attn + half*32;
        float acc = 0.f;
        #pragma unroll
        for (int k0 = 0; k0 < 32; k0 += 4) {
            float4 xp4 = *(const float4*)(xp + k0);
            float4 xq4 = *(const float4*)(xq + k0);
            float a0 = at[k0+0], a1 = at[k0+1], a2 = at[k0+2], a3 = at[k0+3];
            float v0 = tk0 + xp4.x + xq4.x;
            acc = fmaf(a0, silu_f(v0), acc);
            { float tn2 = c2*tk1 - tk0; tk0 = tk1; tk1 = tn2; }
            float v1 = tk0 + xp4.y + xq4.y;
            acc = fmaf(a1, silu_f(v1), acc);
            { float tn2 = c2*tk1 - tk0; tk0 = tk1; tk1 = tn2; }
            float v2 = tk0 + xp4.z + xq4.z;
            acc = fmaf(a2, silu_f(v2), acc);
            { float tn2 = c2*tk1 - tk0; tk0 = tk1; tk1 = tn2; }
            float v3 = tk0 + xp4.w + xq4.w;
            acc = fmaf(a3, silu_f(v3), acc);
            { float tn2 = c2*tk1 - tk0; tk0 = tk1; tk1 = tn2; }
        }
        lg = acc;
    }
    lg += __shfl_xor(lg, 1);
    if (tt < 240 && (tt & 1) == 0) {
        s_logit[pp][qq] = lg;
        s_logit[qq][pp] = lg;
    }
    __syncthreads();
    // column softmax: thread (q = tt>>4, p = tt&15); shfl groups of 16 share q
    {
        int q = tt >> 4, p = tt & 15;
        float l = s_logit[p][q];
        float m = l;
        m = fmaxf(m, __shfl_xor(m, 1));
        m = fmaxf(m, __shfl_xor(m, 2));
        m = fmaxf(m, __shfl_xor(m, 4));
        m = fmaxf(m, __shfl_xor(m, 8));
        float e = __expf(l - m);
        float z = e;
        z += __shfl_xor(z, 1);
        z += __shfl_xor(z, 2);
        z += __shfl_xor(z, 4);
        z += __shfl_xor(z, 8);
        s_a[p][q] = e * __builtin_amdgcn_rcpf(z);   // attention weight, zi folded in
    }
    __syncthreads();
    // row-sum: thread (p = tt>>4, q = tt&15); sw[p] = sum_q a[p][q]
    {
        int p = tt >> 4, q = tt & 15;
        float a = s_a[p][q];
        a += __shfl_xor(a, 1);
        a += __shfl_xor(a, 2);
        a += __shfl_xor(a, 4);
        a += __shfl_xor(a, 8);
        if (q == 0) s_w[p] = a;
    }
    __syncthreads();
    if (tt < 64) {
        float acc = 0.f;
        #pragma unroll
        for (int p = 0; p < 16; ++p) acc += s_w[p] * s_xij[p][tt];
        xn[(size_t)node*64 + tt] = f2b(acc);
    }
}

extern "C" void kernel_launch(void* const* d_in, const int* in_sizes, int n_in,
                              void* d_out, int out_size, void* d_ws, size_t ws_size,
                              hipStream_t stream) {
    (void)in_sizes; (void)n_in; (void)out_size; (void)ws_size;
    const float* r    = (const float*)d_in[0];
    const int*   an   = (const int*)  d_in[1];
    const int*   src  = (const int*)  d_in[2];
    const float* emb  = (const float*)d_in[6];
    const float* Wsrc = (const float*)d_in[7];
    const float* bsrc = (const float*)d_in[8];
    const float* Wdst = (const float*)d_in[9];
    const float* bdst = (const float*)d_in[10];
    const float* Wedge= (const float*)d_in[11];
    const float* bedge= (const float*)d_in[12];
    const float* attn = (const float*)d_in[13];
    const float* W1   = (const float*)d_in[14];
    const float* b1   = (const float*)d_in[15];
    const float* W2   = (const float*)d_in[16];
    const float* b2   = (const float*)d_in[17];
    const float* Wfc  = (const float*)d_in[18];
    const float* bfc  = (const float*)d_in[19];

    char* ws = (char*)d_ws;
    float* d_d              = (float*)(ws);                    // 384000 B
    float* d_rhat           = (float*)(ws + 384000);           // 1536000 B
    unsigned short* d_wsdp  = (unsigned short*)(ws + 1920000); // 65536 B (packed wsrc/wdst)
    unsigned short* d_wedgep= (unsigned short*)(ws + 1985536); // 98304 B (packed Wedge)
    unsigned short* d_xjxi  = (unsigned short*)(ws + 7252992); // 1536000 B
    unsigned short* d_table = (unsigned short*)(ws + 8788992); // 393216 B (bf16 eproj table)
    unsigned short* d_xn    = (unsigned short*)(ws + 45652992);// 768000 B
    unsigned short* d_wcomb = (unsigned short*)(ws + 46420992);// 524288 B (packed)
    float* d_bcomb          = (float*)(ws + 46945280);         // 1024 B
    float* d_wfc2           = (float*)(ws + 46946304);         // 4096 B
    unsigned short* d_w1p   = (unsigned short*)(ws + 47048704);// 393216 B (packed, 3 layers)
    float* out = (float*)d_out;

    // prep: pure streaming branches, no LDS (embed relay removed)
    prep_kernel<<<GEOM_BLOCKS + WPACK1_BLOCKS + WSDP_BLOCKS + WPACKE_BLOCKS,
                  256, 0, stream>>>(
        Wsrc, Wdst, W1, Wedge, r, d_d, d_rhat, d_w1p, d_wsdp, d_wedgep);

    // merged gemm0 (fused embed) [0,375) + wcomb [375,444) + MFMA table build [444,460)
    eplg_kernel<<<375 + 69 + 16, 256, 0, stream>>>(
        an, emb, d_wsdp, bsrc, bdst, d_xjxi,
        Wsrc, Wdst, W2, b2, Wfc, bfc,
        d_wcomb, d_bcomb, d_wfc2,
        d_wedgep, bedge, d_table, out);

    // ---- layer 0 ----
    angle_kernel<<<N_NODES, 256, 0, stream>>>(
        d_xjxi, d_table, 0, d_d, d_rhat, src, attn, d_xn);
    ffw_kernel<<<dim3(375, 2), 256, 0, stream>>>(
        d_xn, d_w1p, b1, d_wcomb, d_bcomb, d_xjxi, N_NODES);

    // ---- layer 1 ----
    angle_kernel<<<N_NODES, 256, 0, stream>>>(
        d_xjxi, d_table, 64, d_d, d_rhat, src, attn + 64, d_xn);
    ffw_kernel<<<dim3(375, 2), 256, 0, stream>>>(
        d_xn, d_w1p + 65536, b1 + 1024, d_wcomb + 131072, d_bcomb + 128, d_xjxi, N_NODES);

    // ---- layer 2 (FF + final reduction, packed W1, barrier-free loop) ----
    angle_kernel<<<N_NODES, 256, 0, stream>>>(
        d_xjxi, d_table, 128, d_d, d_rhat, src, attn + 128, d_xn);
    ffa_kernel<<<375, 256, 0, stream>>>(
        d_xn, d_w1p + 131072, b1 + 2048, d_wfc2, out, N_NODES);
}